// Round 8
// baseline (341.940 us; speedup 1.0000x reference)
//
#include <hip/hip_runtime.h>

// PointNetLayer round 8: edge-kernel critical path. Single full-wave gather
// (lane L owns edge W+L; lanes>=32 hold pass-1 msg in VGPRs), pass-invariant
// w1 fragments + biases hoisted out of the pass loop. Aux pipeline unchanged.

typedef __attribute__((ext_vector_type(8))) _Float16 half8;
typedef __attribute__((ext_vector_type(4))) float floatx4;

#define RELU(v) fmaxf((v), 0.0f)
#define LDS_FENCE() asm volatile("s_waitcnt lgkmcnt(0)" ::: "memory")

// ---------- pass 1: weight prep (blocks 0..7) + histogram with rank (blocks 8..) ----------
__global__ void count_prep_kernel(const int* __restrict__ ei, int E,
                                  int* __restrict__ cnt, int* __restrict__ rnk,
                                  const float* __restrict__ w1, const float* __restrict__ w2,
                                  const float* __restrict__ w3,
                                  _Float16* __restrict__ w1img, _Float16* __restrict__ w2img,
                                  _Float16* __restrict__ w3img)
{
    const int b = blockIdx.x;
    if (b < 8) {
        const int t = b * 256 + threadIdx.x;
        const int stride = 8 * 256;
        for (int i = t; i < 128 * 64; i += stride) {
            int o = i >> 6, cpr = (i >> 3) & 7, j = i & 7;
            int k = ((cpr ^ (o & 7)) << 3) | j;
            w2img[i] = (_Float16)w2[k * 128 + o];
        }
        for (int i = t; i < 64 * 128; i += stride) {
            int o = i >> 7, cpr = (i >> 3) & 15, j = i & 7;
            int kc = cpr ^ (o & 7);
            int k = (kc << 3) | j;
            w3img[i] = (_Float16)w3[k * 64 + o];
        }
        for (int i = t; i < 64 * 32; i += stride) {
            int o = i >> 5, c = (i >> 3) & 3, j = i & 7;
            int k = ((c ^ (o & 3)) << 3) | j;
            w1img[i] = (k < 19) ? (_Float16)w1[k * 64 + o] : (_Float16)0.0f;
        }
    } else {
        const int e = (b - 8) * 256 + threadIdx.x;
        if (e < E) rnk[e] = atomicAdd(&cnt[ei[E + e]], 1);
    }
}

// ---------- pass 2: parallel exclusive scan ----------
__global__ __launch_bounds__(1024)
void scan1_kernel(const int* __restrict__ cnt, int* __restrict__ cur,
                  int* __restrict__ bsum, int N)
{
    __shared__ int sh[1024];
    const int t = threadIdx.x, b = blockIdx.x;
    const int idx = b * 1024 + t;
    int v = (idx < N) ? cnt[idx] : 0;
    sh[t] = v;
    __syncthreads();
    for (int off = 1; off < 1024; off <<= 1) {
        int o = (t >= off) ? sh[t - off] : 0;
        __syncthreads();
        sh[t] += o;
        __syncthreads();
    }
    if (idx < N) cur[idx] = sh[t] - v;
    if (t == 1023) bsum[b] = sh[t];
}

__global__ __launch_bounds__(128)
void scan2_kernel(int* __restrict__ bsum, int NB)
{
    __shared__ int sh[128];
    const int t = threadIdx.x;
    int v = (t < NB) ? bsum[t] : 0;
    sh[t] = v;
    __syncthreads();
    for (int off = 1; off < 128; off <<= 1) {
        int o = (t >= off) ? sh[t - off] : 0;
        __syncthreads();
        sh[t] += o;
        __syncthreads();
    }
    if (t < NB) bsum[t] = sh[t] - v;
}

// ---------- pass 3: atomic-free scatter ----------
__global__ void scatter_kernel(const int* __restrict__ ei, int E,
                               const int* __restrict__ cur, const int* __restrict__ bsum,
                               const int* __restrict__ rnk, int2* __restrict__ ep)
{
    int e = blockIdx.x * blockDim.x + threadIdx.x;
    if (e >= E) return;
    int s = ei[e], d = ei[E + e];
    int p = cur[d] + bsum[d >> 10] + rnk[e];
    ep[p] = make_int2(s, d);
}

__device__ __forceinline__ void load_msg(float* msg, int s, int d,
                                         const float* __restrict__ x,
                                         const float* __restrict__ pos)
{
    const float4* xv = reinterpret_cast<const float4*>(x + (size_t)s * 16);
    float4 x0 = xv[0], x1 = xv[1], x2 = xv[2], x3 = xv[3];
    msg[0] = x0.x;  msg[1] = x0.y;  msg[2] = x0.z;  msg[3] = x0.w;
    msg[4] = x1.x;  msg[5] = x1.y;  msg[6] = x1.z;  msg[7] = x1.w;
    msg[8] = x2.x;  msg[9] = x2.y;  msg[10] = x2.z; msg[11] = x2.w;
    msg[12] = x3.x; msg[13] = x3.y; msg[14] = x3.z; msg[15] = x3.w;
    msg[16] = pos[(size_t)s * 3 + 0] - pos[(size_t)d * 3 + 0];
    msg[17] = pos[(size_t)s * 3 + 1] - pos[(size_t)d * 3 + 1];
    msg[18] = pos[(size_t)s * 3 + 2] - pos[(size_t)d * 3 + 2];
}

// ---------- main fused edge kernel ----------
// 256 thr = 4 waves, 256 edges/block, wave owns 64 edges (2 passes of 32).
// Round 8: single full-wave gather at wave start (lane L = edge W+L); lanes>=32
// hold pass-1 msg in VGPRs until pass 1; w1 frags + biases hoisted.
__global__ __launch_bounds__(256, 2)
void edge_mlp_mfma(const float* __restrict__ x, const float* __restrict__ pos,
                   const _Float16* __restrict__ w1img, const float* __restrict__ b1,
                   const _Float16* __restrict__ w2img, const float* __restrict__ b2,
                   const _Float16* __restrict__ w3img, const float* __restrict__ b3,
                   const int2* __restrict__ ep, int E, float* __restrict__ aggf)
{
    __shared__ __align__(16) _Float16 w2s[128 * 64];    // 16 KB
    __shared__ __align__(16) _Float16 w3s[64 * 128];    // 16 KB
    __shared__ __align__(16) _Float16 w1s[64 * 32];     // 4 KB
    __shared__ __align__(16) float b1s[64], b2s[128], b3s[64];
    __shared__ __align__(16) int2 sd[256];              // 2 KB
    __shared__ __align__(16) float scratch[4][2048];    // 8 KB per wave

    const int t  = threadIdx.x;
    const int bs = blockIdx.x * 256;

    {
        const int4* s2 = (const int4*)w2img;
        int4* d2 = (int4*)w2s;
        for (int i = t; i < 1024; i += 256) d2[i] = s2[i];
        const int4* s3 = (const int4*)w3img;
        int4* d3 = (int4*)w3s;
        for (int i = t; i < 1024; i += 256) d3[i] = s3[i];
        const int4* s1 = (const int4*)w1img;
        int4* d1 = (int4*)w1s;
        if (t < 256) d1[t] = s1[t];
    }
    if (t < 64) { b1s[t] = b1[t]; b3s[t] = b3[t]; }
    if (t < 128) b2s[t] = b2[t];
    sd[t] = ep[min(bs + t, E - 1)];
    __syncthreads();

    const int lane = t & 63;
    const int w    = t >> 6;
    const int g    = lane >> 4;
    const int li   = lane & 15;
    const int W    = bs + w * 64;
    float*    h3w  = &scratch[w][0];
    _Float16* msgh = (_Float16*)&scratch[w][0];      // [32e][4c][8j] fp16, 2KB
    _Float16* h2h  = (_Float16*)&scratch[w][0];      // [32e][8c][8j] fp16, 4KB
    _Float16* h1s  = (_Float16*)&scratch[w][1024];   // [32e][8c][8j] fp16, 4KB

    const int n = min(64, E - W);
    const int c = lane;
    int prevd = -2, nextd = -2;
    if (n > 0) {
        prevd = (W == 0) ? -2 : __builtin_amdgcn_readfirstlane((w > 0) ? sd[w * 64 - 1].y : ep[W - 1].y);
        nextd = (W + n >= E) ? -2 : __builtin_amdgcn_readfirstlane((w < 3) ? sd[(w + 1) * 64].y : ep[W + 64].y);
    }
    int curd = -1;
    float mv = 0.0f;

    // ---- single full-wave gather: lane L owns edge W+L ----
    half8 mreg[4];
    {
        int2 e0 = sd[w * 64 + lane];
        float m[19];
        load_msg(m, e0.x, e0.y, x, pos);
        _Float16 hv[32];
        #pragma unroll
        for (int k = 0; k < 19; ++k) hv[k] = (_Float16)m[k];
        #pragma unroll
        for (int k = 19; k < 32; ++k) hv[k] = (_Float16)0.0f;
        #pragma unroll
        for (int cch = 0; cch < 4; ++cch) {
            half8 hh;
            #pragma unroll
            for (int j = 0; j < 8; ++j) hh[j] = hv[cch * 8 + j];
            mreg[cch] = hh;
        }
    }

    // ---- pass-invariant: w1 fragments + biases ----
    half8 w1f[4];
    #pragma unroll
    for (int nf = 0; nf < 4; ++nf) {
        const int o = nf * 16 + li;
        w1f[nf] = *(const half8*)&w1s[o * 32 + (g ^ (o & 3)) * 8];
    }
    float b1v[4], b2v[8], b3v[4];
    #pragma unroll
    for (int nf = 0; nf < 4; ++nf) { b1v[nf] = b1s[nf * 16 + li]; b3v[nf] = b3s[nf * 16 + li]; }
    #pragma unroll
    for (int i = 0; i < 8; ++i) b2v[i] = b2s[i * 16 + li];

    #pragma unroll
    for (int p = 0; p < 2; ++p) {
        // ---- msg write for this pass (from held registers) ----
        {
            const int el = lane & 31;
            const int sw = (el >> 1) & 3;
            bool mine = (p == 0) ? (lane < 32) : (lane >= 32);
            if (mine) {
                #pragma unroll
                for (int cch = 0; cch < 4; ++cch)
                    *(half8*)&msgh[el * 32 + (cch ^ sw) * 8] = mreg[cch];
            }
        }
        LDS_FENCE();
        __builtin_amdgcn_sched_barrier(0);

        // ---- layer 1 MFMA: [32e x 32k] x [32k x 64o] ----
        {
            floatx4 acc1[2][4];
            #pragma unroll
            for (int nf = 0; nf < 4; ++nf) {
                float bv = b1v[nf];
                acc1[0][nf] = (floatx4){bv, bv, bv, bv};
                acc1[1][nf] = (floatx4){bv, bv, bv, bv};
            }
            #pragma unroll
            for (int mf = 0; mf < 2; ++mf) {
                const int el = mf * 16 + li;
                half8 af = *(const half8*)&msgh[el * 32 + (g ^ ((el >> 1) & 3)) * 8];
                #pragma unroll
                for (int nf = 0; nf < 4; ++nf)
                    acc1[mf][nf] = __builtin_amdgcn_mfma_f32_16x16x32_f16(af, w1f[nf], acc1[mf][nf], 0, 0, 0);
            }
            LDS_FENCE();
            #pragma unroll
            for (int mf = 0; mf < 2; ++mf)
                #pragma unroll
                for (int nf = 0; nf < 4; ++nf)
                    #pragma unroll
                    for (int r = 0; r < 4; ++r) {
                        const int e2 = mf * 16 + g * 4 + r;
                        const int o  = nf * 16 + li;
                        const int cpr = (o >> 3) ^ (e2 & 7);
                        h1s[e2 * 64 + cpr * 8 + (o & 7)] = (_Float16)RELU(acc1[mf][nf][r]);
                    }
        }
        LDS_FENCE();
        __builtin_amdgcn_sched_barrier(0);

        // ---- load L2 A-frags from h1s ----
        half8 afr[2][2];
        #pragma unroll
        for (int ks = 0; ks < 2; ++ks)
            #pragma unroll
            for (int mf = 0; mf < 2; ++mf) {
                const int e2 = mf * 16 + li;
                const int cpr = (ks * 4 + g) ^ (e2 & 7);
                afr[mf][ks] = *(const half8*)&h1s[e2 * 64 + cpr * 8];
            }

        // ---- L2 (double-pumped 64-col halves) + L3 accumulate ----
        floatx4 acc3[2][4];
        #pragma unroll
        for (int nf = 0; nf < 4; ++nf) {
            float bv = b3v[nf];
            acc3[0][nf] = (floatx4){bv, bv, bv, bv};
            acc3[1][nf] = (floatx4){bv, bv, bv, bv};
        }

        #pragma unroll
        for (int hf = 0; hf < 2; ++hf) {
            floatx4 acc2[2][4];
            #pragma unroll
            for (int nf = 0; nf < 4; ++nf) {
                float bv = b2v[hf * 4 + nf];
                acc2[0][nf] = (floatx4){bv, bv, bv, bv};
                acc2[1][nf] = (floatx4){bv, bv, bv, bv};
            }
            #pragma unroll
            for (int ks = 0; ks < 2; ++ks) {
                #pragma unroll
                for (int nf = 0; nf < 4; ++nf) {
                    const int o = hf * 64 + nf * 16 + li;
                    const int cpr = (ks * 4 + g) ^ (o & 7);
                    half8 bfr = *(const half8*)&w2s[o * 64 + cpr * 8];
                    acc2[0][nf] = __builtin_amdgcn_mfma_f32_16x16x32_f16(afr[0][ks], bfr, acc2[0][nf], 0, 0, 0);
                    acc2[1][nf] = __builtin_amdgcn_mfma_f32_16x16x32_f16(afr[1][ks], bfr, acc2[1][nf], 0, 0, 0);
                }
            }
            LDS_FENCE();
            #pragma unroll
            for (int mf = 0; mf < 2; ++mf)
                #pragma unroll
                for (int nf = 0; nf < 4; ++nf)
                    #pragma unroll
                    for (int r = 0; r < 4; ++r) {
                        const int e2 = mf * 16 + g * 4 + r;
                        const int ol = nf * 16 + li;
                        const int cpr = (ol >> 3) ^ (e2 & 7);
                        h2h[e2 * 64 + cpr * 8 + (ol & 7)] = (_Float16)RELU(acc2[mf][nf][r]);
                    }
            LDS_FENCE();
            __builtin_amdgcn_sched_barrier(0);
            #pragma unroll
            for (int ks_l = 0; ks_l < 2; ++ks_l) {
                const int ksg = hf * 2 + ks_l;
                half8 a2[2], b3f[4];
                #pragma unroll
                for (int mf = 0; mf < 2; ++mf) {
                    const int e2 = mf * 16 + li;
                    const int ca = (ks_l * 4 + g) ^ (e2 & 7);
                    a2[mf] = *(const half8*)&h2h[e2 * 64 + ca * 8];
                }
                #pragma unroll
                for (int nf = 0; nf < 4; ++nf) {
                    const int o = nf * 16 + li;
                    const int cb = (ksg * 4 + g) ^ (o & 7);
                    b3f[nf] = *(const half8*)&w3s[o * 128 + cb * 8];
                }
                #pragma unroll
                for (int mf = 0; mf < 2; ++mf)
                    #pragma unroll
                    for (int nf = 0; nf < 4; ++nf)
                        acc3[mf][nf] = __builtin_amdgcn_mfma_f32_16x16x32_f16(a2[mf], b3f[nf], acc3[mf][nf], 0, 0, 0);
            }
        } // hf

        // ---- h3 epilogue ----
        LDS_FENCE();
        #pragma unroll
        for (int mf = 0; mf < 2; ++mf)
            #pragma unroll
            for (int nf = 0; nf < 4; ++nf)
                #pragma unroll
                for (int r = 0; r < 4; ++r) {
                    const int e3 = mf * 16 + g * 4 + r;
                    const int o  = nf * 16 + li;
                    h3w[e3 * 64 + (o ^ (((e3 >> 2) & 3) << 4))] = RELU(acc3[mf][nf][r]);
                }
        LDS_FENCE();
        __builtin_amdgcn_sched_barrier(0);

        // ---- per-pass sorted-run scan ----
        {
            const int lim = min(32, n - p * 32);
            for (int i = 0; i < lim; ++i) {
                const int d = __builtin_amdgcn_readfirstlane(sd[w * 64 + p * 32 + i].y);
                const float v = h3w[i * 64 + (c ^ (((i >> 2) & 3) << 4))];
                if (d != curd) {
                    if (curd >= 0) {
                        if (curd == prevd || curd == nextd)
                            atomicMax((int*)&aggf[(size_t)curd * 64 + c], __float_as_int(mv));
                        else
                            aggf[(size_t)curd * 64 + c] = mv;
                    }
                    curd = d;
                    mv = v;
                } else {
                    mv = fmaxf(mv, v);
                }
            }
        }
        LDS_FENCE();
    } // p

    if (curd >= 0) {
        if (curd == prevd || curd == nextd)
            atomicMax((int*)&aggf[(size_t)curd * 64 + c], __float_as_int(mv));
        else
            aggf[(size_t)curd * 64 + c] = mv;
    }
}

// ---------- node MLP: out = relu(agg @ wg + bg) ----------
__global__ __launch_bounds__(256, 4)
void node_out_kernel(const float* __restrict__ agg, const float* __restrict__ wg,
                     const float* __restrict__ bg, float* __restrict__ out, int N)
{
    __shared__ float wgs[64 * 64];
    for (int i = threadIdx.x; i < 64 * 64; i += blockDim.x) wgs[i] = wg[i];
    __syncthreads();

    const int t = blockIdx.x * blockDim.x + threadIdx.x;
    const int nidx = t >> 4;
    const int og = t & 15;
    if (nidx >= N) return;

    const float4* aggv = reinterpret_cast<const float4*>(agg + (size_t)nidx * 64);
    const float4* wgsv = reinterpret_cast<const float4*>(wgs);

    float4 acc = reinterpret_cast<const float4*>(bg)[og];
    #pragma unroll
    for (int kg = 0; kg < 16; ++kg) {
        float4 a = aggv[kg];
        float4 w0 = wgsv[(kg * 4 + 0) * 16 + og];
        float4 w1 = wgsv[(kg * 4 + 1) * 16 + og];
        float4 w2 = wgsv[(kg * 4 + 2) * 16 + og];
        float4 w3 = wgsv[(kg * 4 + 3) * 16 + og];
        acc.x += a.x * w0.x + a.y * w1.x + a.z * w2.x + a.w * w3.x;
        acc.y += a.x * w0.y + a.y * w1.y + a.z * w2.y + a.w * w3.y;
        acc.z += a.x * w0.z + a.y * w1.z + a.z * w2.z + a.w * w3.z;
        acc.w += a.x * w0.w + a.y * w1.w + a.z * w2.w + a.w * w3.w;
    }
    float4 r;
    r.x = RELU(acc.x); r.y = RELU(acc.y); r.z = RELU(acc.z); r.w = RELU(acc.w);
    reinterpret_cast<float4*>(out)[(size_t)nidx * 16 + og] = r;
}

extern "C" void kernel_launch(void* const* d_in, const int* in_sizes, int n_in,
                              void* d_out, int out_size, void* d_ws, size_t ws_size,
                              hipStream_t stream)
{
    const float* x   = (const float*)d_in[0];
    const float* pos = (const float*)d_in[1];
    const float* w1  = (const float*)d_in[2];
    const float* b1  = (const float*)d_in[3];
    const float* w2  = (const float*)d_in[4];
    const float* b2  = (const float*)d_in[5];
    const float* w3  = (const float*)d_in[6];
    const float* b3  = (const float*)d_in[7];
    const float* wg  = (const float*)d_in[8];
    const float* bg  = (const float*)d_in[9];
    const int*   ei  = (const int*)d_in[10];

    const int N = in_sizes[0] / 16;
    const int E = in_sizes[10] / 2;

    // ws layout (int elements): [cnt N][agg N*64][cur N][bsum 128][ep 2E][rank E][images]
    int* wsi  = (int*)d_ws;
    int* cnt  = wsi;                               // [N]
    int* agg  = wsi + N;                           // [N*64]
    int* cur  = wsi + N + N * 64;                  // [N]
    int* bsum = wsi + N * 66;                      // [128]
    int2* ep  = (int2*)(wsi + N * 66 + 128);       // [E]
    int* rnk  = wsi + N * 66 + 128 + 2 * E;        // [E]
    _Float16* w2img = (_Float16*)(wsi + N * 66 + 128 + 3 * E);  // [8192]
    _Float16* w3img = w2img + 8192;                              // [8192]
    _Float16* w1img = w3img + 8192;                              // [2048]

    hipMemsetAsync(cnt, 0, (size_t)N * 65 * sizeof(int), stream);

    const int eb = (E + 255) / 256;
    const int NB = (N + 1023) / 1024;
    count_prep_kernel<<<eb + 8, 256, 0, stream>>>(ei, E, cnt, rnk,
                                                  w1, w2, w3, w1img, w2img, w3img);
    scan1_kernel<<<NB, 1024, 0, stream>>>(cnt, cur, bsum, N);
    scan2_kernel<<<1, 128, 0, stream>>>(bsum, NB);
    scatter_kernel<<<eb, 256, 0, stream>>>(ei, E, cur, bsum, rnk, ep);
    edge_mlp_mfma<<<(E + 255) / 256, 256, 0, stream>>>(
        x, pos, w1img, b1, w2img, b2, w3img, b3, ep, E, (float*)agg);
    node_out_kernel<<<(N * 16 + 255) / 256, 256, 0, stream>>>(
        (const float*)agg, wg, bg, (float*)d_out, N);
}